// Round 2
// baseline (111.704 us; speedup 1.0000x reference)
//
#include <hip/hip_runtime.h>

typedef float f4 __attribute__((ext_vector_type(4)));

constexpr int N_  = 4;
constexpr int C_  = 320;
constexpr int H_  = 80;
constexpr int W_  = 160;
constexpr int G_  = 40;
constexpr int CPG = 8;      // channels per group
constexpr int D_  = 48;     // max disparity
constexpr int PAD = 48;     // zero pad in front of R rows
constexpr int RW  = PAD + W_;   // 208 floats per R row
constexpr int H2  = 2;      // h-rows per block
// tiles: 4w x 8d, per h-row: (160/4)*(48/8) = 40*6 = 240; per block: 480

__global__ __launch_bounds__(256) void gw_cost_kernel(const float* __restrict__ Lg,
                                                      const float* __restrict__ Rg,
                                                      float* __restrict__ out) {
    // Ls[c][hh][w]  flat: c*320 + hh*160 + w        (10240 B)
    // Rs[c][hh][rw] flat: c*416 + hh*208 + rw       (13312 B), rw<48 is zero pad
    __shared__ float Ls[CPG * H2 * W_];
    __shared__ float Rs[CPG * H2 * RW];

    const int blk = blockIdx.x;            // ((n*G + g)*(H/2) + h2)
    const int h2 = blk % (H_ / H2);
    const int g  = (blk / (H_ / H2)) % G_;
    const int n  = blk / ((H_ / H2) * G_);
    const int h0 = h2 * H2;

    const int tid = threadIdx.x;

    // ---- stage global -> LDS: per channel, 2 contiguous h-rows = 1280 B ----
    for (int i = tid; i < CPG * (H2 * W_ / 4); i += 256) {   // 640 f4 per input
        const int c   = i / 80;
        const int rem = i % 80;            // rem = hh*40 + w4
        const size_t gb = ((size_t)(n * C_ + g * CPG + c) * H_ + h0) * W_ + rem * 4;
        *(f4*)&Ls[c * 320 + rem * 4] = *(const f4*)(Lg + gb);
        const int hh = rem / 40, w4 = rem % 40;
        *(f4*)&Rs[c * 416 + hh * 208 + PAD + w4 * 4] = *(const f4*)(Rg + gb);
    }
    for (int i = tid; i < CPG * H2 * (PAD / 4); i += 256) {  // 192 zero f4
        const int c   = i / 24;
        const int rem = i % 24;
        const int hh = rem / 12, p4 = rem % 12;
        *(f4*)&Rs[c * 416 + hh * 208 + p4 * 4] = (f4)(0.0f);
    }
    __syncthreads();

    // ---- compute: each thread owns 4w x 8d tiles ----
    for (int t = tid; t < H2 * 240; t += 256) {
        const int hh  = t / 240;
        const int rem = t % 240;
        const int tw = rem / 6;
        const int td = rem % 6;
        const int w0 = tw * 4;
        const int d0 = td * 8;
        const int r0 = w0 - d0 + PAD;      // in [8, 204]

        f4 acc[4][2] = {};

        #pragma unroll
        for (int c = 0; c < CPG; ++c) {
            const f4 lv = *(const f4*)&Ls[c * 320 + hh * 160 + w0];
            const float* rp = &Rs[c * 416 + hh * 208 + (r0 - 8)];  // 16B-aligned
            const f4 ra = *(const f4*)(rp);
            const f4 rb = *(const f4*)(rp + 4);
            const f4 rc = *(const f4*)(rp + 8);
            float r[12];
            #pragma unroll
            for (int k = 0; k < 4; ++k) { r[k] = ra[k]; r[4 + k] = rb[k]; r[8 + k] = rc[k]; }
            // out(w0+i, d0+j) += L[w0+i] * R[r0 + i - j]  -> r[8 + i - j], in r[1..11]
            #pragma unroll
            for (int i = 0; i < 4; ++i) {
                #pragma unroll
                for (int j = 0; j < 8; ++j) {
                    acc[i][j >> 2][j & 3] += lv[i] * r[8 + i - j];
                }
            }
        }

        const size_t ob = ((size_t)((n * G_ + g) * H_ + h0 + hh)) * (W_ * D_);
        float* op = out + ob + (size_t)w0 * D_ + d0;
        #pragma unroll
        for (int i = 0; i < 4; ++i) {
            *(f4*)(op + i * D_)     = acc[i][0] * 0.125f;
            *(f4*)(op + i * D_ + 4) = acc[i][1] * 0.125f;
        }
    }
}

extern "C" void kernel_launch(void* const* d_in, const int* in_sizes, int n_in,
                              void* d_out, int out_size, void* d_ws, size_t ws_size,
                              hipStream_t stream) {
    const float* Lg = (const float*)d_in[0];
    const float* Rg = (const float*)d_in[1];
    float* out = (float*)d_out;

    const int nblocks = N_ * G_ * (H_ / H2);   // 6400 blocks
    gw_cost_kernel<<<dim3(nblocks), dim3(256), 0, stream>>>(Lg, Rg, out);
}